// Round 1
// baseline (42.445 us; speedup 1.0000x reference)
//
#include <hip/hip_runtime.h>

#define N_EXPERTS 8

// ---------------------------------------------------------------------------
// Kernel 1: compute per-token weight scale with capacity-based dropping.
// T = 32768 flat assignments, 1 block x 1024 threads, 32 entries/thread.
// valid(t) iff (# of t' < t with expert[t']==expert[t]) < C.
// scale[token] = sum over its top_k entries of (valid ? w : 0).
// Per-thread histogram packed 8x8bit in a u64 (max 32 per lane -> fits) to
// avoid runtime-indexed register arrays (scratch hazard, rule #20).
// ---------------------------------------------------------------------------
__global__ __launch_bounds__(1024) void scale_kernel(
    const int* __restrict__ te, const float* __restrict__ ew,
    float* __restrict__ scale, int C) {
  __shared__ int hist[1024][N_EXPERTS + 1];  // +1 pad: avoid 8-way bank conflict
  const int tid = threadIdx.x;
  const int base = tid * 32;

  // ---- pass 1: packed per-chunk histogram -------------------------------
  const int4* te4 = reinterpret_cast<const int4*>(te + base);
  int4 tebuf[8];
#pragma unroll
  for (int q = 0; q < 8; ++q) tebuf[q] = te4[q];

  unsigned long long cnt64 = 0ull;
#pragma unroll
  for (int q = 0; q < 8; ++q) {
    cnt64 += 1ull << (8 * (tebuf[q].x & 7));
    cnt64 += 1ull << (8 * (tebuf[q].y & 7));
    cnt64 += 1ull << (8 * (tebuf[q].z & 7));
    cnt64 += 1ull << (8 * (tebuf[q].w & 7));
  }
#pragma unroll
  for (int e = 0; e < N_EXPERTS; ++e)
    hist[tid][e] = (int)((cnt64 >> (8 * e)) & 255);
  __syncthreads();

  // ---- inclusive Hillis-Steele scan over the 1024 chunks, per expert ----
  for (int s = 1; s < 1024; s <<= 1) {
    int v[N_EXPERTS];
    if (tid >= s) {
#pragma unroll
      for (int e = 0; e < N_EXPERTS; ++e) v[e] = hist[tid - s][e];
    }
    __syncthreads();
    if (tid >= s) {
#pragma unroll
      for (int e = 0; e < N_EXPERTS; ++e) hist[tid][e] += v[e];
    }
    __syncthreads();
  }
  // hist[tid][e] is now the INCLUSIVE prefix (sum of chunks 0..tid).
  // exclusive prefix for this chunk = hist[tid][e] - own count (from cnt64).

  // ---- pass 2: ranks + weight accumulation (2 entries per token) --------
  const float4* ew4 = reinterpret_cast<const float4*>(ew + base);
  unsigned long long c2 = 0ull;  // running local rank, packed
#pragma unroll
  for (int q = 0; q < 8; ++q) {  // 4 entries = 2 tokens per q
    float4 w4 = ew4[q];
    const int ee[4] = {tebuf[q].x & 7, tebuf[q].y & 7, tebuf[q].z & 7,
                       tebuf[q].w & 7};
    const float wv[4] = {w4.x, w4.y, w4.z, w4.w};
    float s01 = 0.f, s23 = 0.f;
#pragma unroll
    for (int k = 0; k < 4; ++k) {
      const int e = ee[k];
      const int lr = (int)((c2 >> (8 * e)) & 255);
      c2 += 1ull << (8 * e);
      const int cnt_e = (int)((cnt64 >> (8 * e)) & 255);
      const int rank = hist[tid][e] - cnt_e + lr;  // stable global rank in bin
      if (rank < C) {
        if (k < 2) s01 += wv[k]; else s23 += wv[k];
      }
    }
    scale[tid * 16 + q * 2 + 0] = s01;
    scale[tid * 16 + q * 2 + 1] = s23;
  }
}

// ---------------------------------------------------------------------------
// Kernel 2: out[i] = x[i] * scale[i / 1024] + bias[i % 1024], float4-vectorized.
// d = 1024 floats/row -> 256 float4/row (hardcoded shift/mask).
// ---------------------------------------------------------------------------
__global__ __launch_bounds__(256) void apply_kernel(
    const float* __restrict__ x, const float* __restrict__ scale,
    const float* __restrict__ bias, float* __restrict__ out, int total4) {
  const float4* __restrict__ x4 = reinterpret_cast<const float4*>(x);
  const float4* __restrict__ b4 = reinterpret_cast<const float4*>(bias);
  float4* __restrict__ o4 = reinterpret_cast<float4*>(out);
  const int stride = gridDim.x * blockDim.x;
  for (int idx = blockIdx.x * blockDim.x + threadIdx.x; idx < total4;
       idx += stride) {
    const int row = idx >> 8;   // / (1024/4)
    const int col = idx & 255;  // % (1024/4)
    const float s = scale[row];
    const float4 xv = x4[idx];
    const float4 bv = b4[col];
    float4 ov;
    ov.x = xv.x * s + bv.x;
    ov.y = xv.y * s + bv.y;
    ov.z = xv.z * s + bv.z;
    ov.w = xv.w * s + bv.w;
    o4[idx] = ov;
  }
}

extern "C" void kernel_launch(void* const* d_in, const int* in_sizes, int n_in,
                              void* d_out, int out_size, void* d_ws,
                              size_t ws_size, hipStream_t stream) {
  // setup_inputs order: x, cond, mask, scores, expert_weights, top_experts, bias
  const float* x    = (const float*)d_in[0];
  const float* ew   = (const float*)d_in[4];
  const int*   te   = (const int*)d_in[5];
  const float* bias = (const float*)d_in[6];
  float* out   = (float*)d_out;
  float* scale = (float*)d_ws;  // 16384 floats

  const int T = in_sizes[5];          // 32768 flat assignments
  const int C = T / N_EXPERTS;        // 4096 expert capacity

  scale_kernel<<<1, 1024, 0, stream>>>(te, ew, scale, C);

  const int total4 = in_sizes[0] / 4; // 4,194,304 float4
  apply_kernel<<<2048, 256, 0, stream>>>(x, scale, bias, out, total4);
}

// Round 2
// 33.808 us; speedup vs baseline: 1.2555x; 1.2555x over previous
//
#include <hip/hip_runtime.h>

#define N_EXPERTS 8
typedef unsigned long long u64;

// Packed per-expert counts: experts 0-3 in c0, 4-7 in c1, 16-bit fields.
__device__ __forceinline__ void packed_add(u64& c0, u64& c1, int e) {
  if (e < 4) c0 += 1ull << (16 * e);
  else       c1 += 1ull << (16 * (e - 4));
}
__device__ __forceinline__ int packed_get(u64 c0, u64 c1, int e) {
  return (e < 4) ? (int)((c0 >> (16 * e)) & 0xFFFF)
                 : (int)((c1 >> (16 * (e - 4))) & 0xFFFF);
}

// ---------------------------------------------------------------------------
// Kernel 1: per-block expert histograms. 32 blocks x 256 thr x 4 entries.
// hist[b*8+e] = count of expert e in block b's chunk of 1024 flat entries.
// ---------------------------------------------------------------------------
__global__ __launch_bounds__(256) void hist_kernel(
    const int* __restrict__ te, int* __restrict__ hist) {
  __shared__ u64 w0[4], w1[4];
  const int tid = threadIdx.x;
  const int lane = tid & 63, wid = tid >> 6;
  const int g = blockIdx.x * 256 + tid;
  const int4 v = reinterpret_cast<const int4*>(te)[g];

  u64 c0 = 0, c1 = 0;
  packed_add(c0, c1, v.x & 7);
  packed_add(c0, c1, v.y & 7);
  packed_add(c0, c1, v.z & 7);
  packed_add(c0, c1, v.w & 7);
#pragma unroll
  for (int m = 1; m < 64; m <<= 1) {
    c0 += __shfl_xor(c0, m);
    c1 += __shfl_xor(c1, m);
  }
  if (lane == 0) { w0[wid] = c0; w1[wid] = c1; }
  __syncthreads();
  if (tid < N_EXPERTS) {
    int s = 0;
#pragma unroll
    for (int ww = 0; ww < 4; ++ww) s += packed_get(w0[ww], w1[ww], tid);
    hist[blockIdx.x * N_EXPERTS + tid] = s;
  }
}

// ---------------------------------------------------------------------------
// Kernel 2: stable global ranks + per-token scale. 32 blocks x 256 thr.
// rank(entry t) = (#same-expert entries in earlier blocks)      [bpre]
//              + (#same-expert in earlier threads of this block) [shfl scan]
//              + (#same-expert earlier within this thread).
// scale[token] = sum of weights of its entries with rank < C.
// ---------------------------------------------------------------------------
__global__ __launch_bounds__(256) void rank_scale_kernel(
    const int* __restrict__ te, const float* __restrict__ ew,
    const int* __restrict__ hist, float* __restrict__ scale, int C) {
  __shared__ int histl[32 * N_EXPERTS];
  __shared__ int bpre[N_EXPERTS];
  __shared__ u64 woff0[4], woff1[4];
  const int tid = threadIdx.x;
  const int lane = tid & 63, wid = tid >> 6;
  const int b = blockIdx.x;
  const int g = b * 256 + tid;

  histl[tid] = hist[tid];  // 256 ints exactly
  __syncthreads();
  if (tid < N_EXPERTS) {
    int s = 0;
    for (int bb = 0; bb < b; ++bb) s += histl[bb * N_EXPERTS + tid];
    bpre[tid] = s;
  }

  const int4 v = reinterpret_cast<const int4*>(te)[g];
  const float4 w = reinterpret_cast<const float4*>(ew)[g];
  const int e0 = v.x & 7, e1 = v.y & 7, e2 = v.z & 7, e3 = v.w & 7;

  u64 c0 = 0, c1 = 0;
  packed_add(c0, c1, e0);
  packed_add(c0, c1, e1);
  packed_add(c0, c1, e2);
  packed_add(c0, c1, e3);

  // wave-inclusive scan
  u64 s0 = c0, s1 = c1;
#pragma unroll
  for (int i = 1; i < 64; i <<= 1) {
    u64 t0 = __shfl_up(s0, i), t1 = __shfl_up(s1, i);
    if (lane >= i) { s0 += t0; s1 += t1; }
  }
  u64 x0 = s0 - c0, x1 = s1 - c1;  // exclusive within wave
  if (lane == 63) { woff0[wid] = s0; woff1[wid] = s1; }
  __syncthreads();  // also covers bpre writes above
  for (int ww = 0; ww < wid; ++ww) { x0 += woff0[ww]; x1 += woff1[ww]; }

  const int r0 = bpre[e0] + packed_get(x0, x1, e0);
  const int r1 = bpre[e1] + packed_get(x0, x1, e1) + (e1 == e0);
  const int r2 = bpre[e2] + packed_get(x0, x1, e2) + (e2 == e0) + (e2 == e1);
  const int r3 = bpre[e3] + packed_get(x0, x1, e3) + (e3 == e0) + (e3 == e1) +
                 (e3 == e2);

  float2 sc;
  sc.x = (r0 < C ? w.x : 0.f) + (r1 < C ? w.y : 0.f);
  sc.y = (r2 < C ? w.z : 0.f) + (r3 < C ? w.w : 0.f);
  reinterpret_cast<float2*>(scale)[g] = sc;
}

// ---------------------------------------------------------------------------
// Kernel 3: out[i] = x[i] * scale[i / 1024] + bias[i % 1024], float4 loads.
// ---------------------------------------------------------------------------
__global__ __launch_bounds__(256) void apply_kernel(
    const float* __restrict__ x, const float* __restrict__ scale,
    const float* __restrict__ bias, float* __restrict__ out, int total4) {
  const float4* __restrict__ x4 = reinterpret_cast<const float4*>(x);
  const float4* __restrict__ b4 = reinterpret_cast<const float4*>(bias);
  float4* __restrict__ o4 = reinterpret_cast<float4*>(out);
  const int stride = gridDim.x * blockDim.x;
  for (int idx = blockIdx.x * blockDim.x + threadIdx.x; idx < total4;
       idx += stride) {
    const int row = idx >> 8;   // / (1024/4)
    const int col = idx & 255;  // % (1024/4)
    const float s = scale[row];
    const float4 xv = x4[idx];
    const float4 bv = b4[col];
    float4 ov;
    ov.x = xv.x * s + bv.x;
    ov.y = xv.y * s + bv.y;
    ov.z = xv.z * s + bv.z;
    ov.w = xv.w * s + bv.w;
    o4[idx] = ov;
  }
}

extern "C" void kernel_launch(void* const* d_in, const int* in_sizes, int n_in,
                              void* d_out, int out_size, void* d_ws,
                              size_t ws_size, hipStream_t stream) {
  // setup_inputs order: x, cond, mask, scores, expert_weights, top_experts, bias
  const float* x    = (const float*)d_in[0];
  const float* ew   = (const float*)d_in[4];
  const int*   te   = (const int*)d_in[5];
  const float* bias = (const float*)d_in[6];
  float* out = (float*)d_out;

  int*   hist  = (int*)d_ws;               // 256 ints (1 KB)
  float* scale = (float*)d_ws + 256;       // 16384 floats

  const int T = in_sizes[5];               // 32768 flat assignments
  const int C = T / N_EXPERTS;             // 4096 expert capacity

  hist_kernel<<<32, 256, 0, stream>>>(te, hist);
  rank_scale_kernel<<<32, 256, 0, stream>>>(te, ew, hist, scale, C);

  const int total4 = in_sizes[0] / 4;      // 4,194,304 float4
  apply_kernel<<<2048, 256, 0, stream>>>(x, scale, bias, out, total4);
}

// Round 3
// 30.271 us; speedup vs baseline: 1.4021x; 1.1168x over previous
//
#include <hip/hip_runtime.h>

#define N_EXPERTS 8
#define ROWS_PB 8   // token rows per block
#define ENT_PB 16   // flat (token,k) assignments per block = ROWS_PB * top_k
typedef unsigned long long u64;

// Packed per-expert counts: experts 0-3 in c0, 4-7 in c1, 16-bit fields.
// Max prefix count per expert = 32768 < 65536: no field overflow.
__device__ __forceinline__ void packed_add(u64& c0, u64& c1, int e) {
  if (e < 4) c0 += 1ull << (16 * e);
  else       c1 += 1ull << (16 * (e - 4));
}
__device__ __forceinline__ int packed_get(u64 c0, u64 c1, int e) {
  return (e < 4) ? (int)((c0 >> (16 * e)) & 0xFFFF)
                 : (int)((c1 >> (16 * (e - 4))) & 0xFFFF);
}

// ---------------------------------------------------------------------------
// Single fused kernel. Block b (2048 blocks x 256 thr):
//   phase 1a: per-expert histogram of te[0 .. 16b)  (L2-resident redundant
//             scan: Sum_b 16b*4B ~ 134 MB of L2 reads ~ 4 us, overlapped)
//   phase 1b: tid0 serial-ranks the block's 16 assignments (stable order),
//             capacity test rank < C, accumulates weights -> scale_s[8]
//   phase 2:  out[row][:] = x[row][:] * scale_s[row] + bias[:], float4
// ---------------------------------------------------------------------------
__global__ __launch_bounds__(256) void fused_kernel(
    const float* __restrict__ x, const int* __restrict__ te,
    const float* __restrict__ ew, const float* __restrict__ bias,
    float* __restrict__ out, int C) {
  __shared__ u64 w0s[4], w1s[4];
  __shared__ float scale_s[ROWS_PB];
  const int tid = threadIdx.x;
  const int lane = tid & 63, wid = tid >> 6;
  const int b = blockIdx.x;
  const int E0 = b * ENT_PB;   // first flat assignment owned by this block
  const int n4 = E0 >> 2;      // int4 elements in the prefix

  const int4* __restrict__ te4 = reinterpret_cast<const int4*>(te);

  // ---- phase 1a: packed per-expert counts of te[0 .. E0) ----------------
  u64 c0 = 0, c1 = 0;
  for (int i = tid; i < n4; i += 256) {
    const int4 v = te4[i];
    packed_add(c0, c1, v.x & 7);
    packed_add(c0, c1, v.y & 7);
    packed_add(c0, c1, v.z & 7);
    packed_add(c0, c1, v.w & 7);
  }
#pragma unroll
  for (int m = 1; m < 64; m <<= 1) {
    c0 += __shfl_xor(c0, m);
    c1 += __shfl_xor(c1, m);
  }
  if (lane == 0) { w0s[wid] = c0; w1s[wid] = c1; }
  __syncthreads();

  // ---- phase 1b: serial stable rank of the block's 16 assignments -------
  if (tid == 0) {
    u64 p0 = w0s[0] + w0s[1] + w0s[2] + w0s[3];
    u64 p1 = w1s[0] + w1s[1] + w1s[2] + w1s[3];
    const float4* __restrict__ ew4 = reinterpret_cast<const float4*>(ew);
#pragma unroll
    for (int q = 0; q < 4; ++q) {
      const int4 v = te4[(E0 >> 2) + q];
      const float4 w = ew4[(E0 >> 2) + q];
      const int ee[4] = {v.x & 7, v.y & 7, v.z & 7, v.w & 7};
      const float wv[4] = {w.x, w.y, w.z, w.w};
      float s01 = 0.f, s23 = 0.f;
#pragma unroll
      for (int k = 0; k < 4; ++k) {
        const int e = ee[k];
        const int r = packed_get(p0, p1, e);
        packed_add(p0, p1, e);
        if (r < C) {
          if (k < 2) s01 += wv[k]; else s23 += wv[k];
        }
      }
      scale_s[q * 2 + 0] = s01;
      scale_s[q * 2 + 1] = s23;
    }
  }
  __syncthreads();

  // ---- phase 2: stream 8 rows (8 x 256 float4) --------------------------
  const float4 bv = reinterpret_cast<const float4*>(bias)[tid];
  const float4* __restrict__ x4 =
      reinterpret_cast<const float4*>(x) + b * (ROWS_PB * 256);
  float4* __restrict__ o4 =
      reinterpret_cast<float4*>(out) + b * (ROWS_PB * 256);
#pragma unroll
  for (int k = 0; k < ROWS_PB; ++k) {
    const float s = scale_s[k];
    const float4 xv = x4[k * 256 + tid];
    float4 ov;
    ov.x = xv.x * s + bv.x;
    ov.y = xv.y * s + bv.y;
    ov.z = xv.z * s + bv.z;
    ov.w = xv.w * s + bv.w;
    o4[k * 256 + tid] = ov;
  }
}

extern "C" void kernel_launch(void* const* d_in, const int* in_sizes, int n_in,
                              void* d_out, int out_size, void* d_ws,
                              size_t ws_size, hipStream_t stream) {
  // setup_inputs order: x, cond, mask, scores, expert_weights, top_experts, bias
  const float* x    = (const float*)d_in[0];
  const float* ew   = (const float*)d_in[4];
  const int*   te   = (const int*)d_in[5];
  const float* bias = (const float*)d_in[6];
  float* out = (float*)d_out;

  const int T = in_sizes[5];       // 32768 flat assignments
  const int C = T / N_EXPERTS;     // 4096 expert capacity
  const int nblocks = (in_sizes[0] / 1024) / ROWS_PB;  // 16384 rows / 8 = 2048

  fused_kernel<<<nblocks, 256, 0, stream>>>(x, te, ew, bias, out, C);
}

// Round 4
// 30.053 us; speedup vs baseline: 1.4123x; 1.0073x over previous
//
#include <hip/hip_runtime.h>

#define N_EXPERTS 8
#define ROWS_PB 8   // token rows per block
#define ENT_PB 16   // flat (token,k) assignments per block
typedef unsigned long long u64;

// Packed per-expert counts: experts 0-3 in c0, 4-7 in c1, 16-bit fields.
// Max per-field value: full prefix (<=32752) + block-local (<=16) < 65536.
__device__ __forceinline__ void packed_add(u64& c0, u64& c1, int e) {
  if (e < 4) c0 += 1ull << (16 * e);
  else       c1 += 1ull << (16 * (e - 4));
}
__device__ __forceinline__ void packed_add_val(u64& c0, u64& c1, int e, int v) {
  if (e < 4) c0 += (u64)v << (16 * e);
  else       c1 += (u64)v << (16 * (e - 4));
}
__device__ __forceinline__ int packed_get(u64 c0, u64 c1, int e) {
  return (e < 4) ? (int)((c0 >> (16 * e)) & 0xFFFF)
                 : (int)((c1 >> (16 * (e - 4))) & 0xFFFF);
}

// ---------------------------------------------------------------------------
// Kernel 1: per-superblock expert histograms. 32 blocks x 256 thr x int4.
// hist[sb*8+e] = count of expert e among entries [sb*1024, (sb+1)*1024).
// ---------------------------------------------------------------------------
__global__ __launch_bounds__(256) void hist_kernel(
    const int* __restrict__ te, int* __restrict__ hist) {
  __shared__ u64 w0s[4], w1s[4];
  const int tid = threadIdx.x;
  const int lane = tid & 63, wid = tid >> 6;
  const int g = blockIdx.x * 256 + tid;
  const int4 v = reinterpret_cast<const int4*>(te)[g];

  u64 c0 = 0, c1 = 0;
  packed_add(c0, c1, v.x & 7);
  packed_add(c0, c1, v.y & 7);
  packed_add(c0, c1, v.z & 7);
  packed_add(c0, c1, v.w & 7);
#pragma unroll
  for (int m = 1; m < 64; m <<= 1) {
    c0 += __shfl_xor(c0, m);
    c1 += __shfl_xor(c1, m);
  }
  if (lane == 0) { w0s[wid] = c0; w1s[wid] = c1; }
  __syncthreads();
  if (tid < N_EXPERTS) {
    int s = 0;
#pragma unroll
    for (int ww = 0; ww < 4; ++ww) s += packed_get(w0s[ww], w1s[ww], tid);
    hist[blockIdx.x * N_EXPERTS + tid] = s;
  }
}

// ---------------------------------------------------------------------------
// Kernel 2 (fused): block b owns rows [8b, 8b+8) = flat entries [16b, 16b+16).
//   prefix(e) over te[0..16b) = sum of hist over superblocks < sb
//                             + count in partial tail [sb*1024, 16b)
//   Both folded into ONE packed shfl/LDS reduction.
//   tid0 serial-ranks the block's 16 entries (stable), rank < C keeps weight.
//   x/bias prefetched BEFORE the prologue so HBM loads hide the L2 latency.
// ---------------------------------------------------------------------------
__global__ __launch_bounds__(256) void fused_kernel(
    const float* __restrict__ x, const int* __restrict__ te,
    const float* __restrict__ ew, const int* __restrict__ hist,
    const float* __restrict__ bias, float* __restrict__ out, int C) {
  __shared__ u64 w0s[4], w1s[4];
  __shared__ float scale_s[ROWS_PB];
  const int tid = threadIdx.x;
  const int lane = tid & 63, wid = tid >> 6;
  const int b = blockIdx.x;
  const int E0 = b * ENT_PB;        // first flat entry of this block
  const int sb = b >> 6;            // full superblocks (1024 entries each)
  const int partial4 = 4 * (b & 63);  // int4 count in the partial tail

  const int4* __restrict__ te4 = reinterpret_cast<const int4*>(te);

  // ---- prefetch the streaming data (issue loads early) ------------------
  const float4* __restrict__ x4 =
      reinterpret_cast<const float4*>(x) + b * (ROWS_PB * 256);
  float4 xv0 = x4[0 * 256 + tid];
  float4 xv1 = x4[1 * 256 + tid];
  float4 xv2 = x4[2 * 256 + tid];
  float4 xv3 = x4[3 * 256 + tid];
  float4 xv4 = x4[4 * 256 + tid];
  float4 xv5 = x4[5 * 256 + tid];
  float4 xv6 = x4[6 * 256 + tid];
  float4 xv7 = x4[7 * 256 + tid];
  const float4 bv = reinterpret_cast<const float4*>(bias)[tid];

  // ---- prologue: prefix counts (hist part + partial tail part) ----------
  u64 c0 = 0, c1 = 0;
  {
    const int bb = tid >> 3;         // superblock index for hist element tid
    const int he = tid & 7;          // expert
    if (bb < sb) packed_add_val(c0, c1, he, hist[tid]);
  }
  if (tid < partial4) {
    const int4 v = te4[sb * 256 + tid];
    packed_add(c0, c1, v.x & 7);
    packed_add(c0, c1, v.y & 7);
    packed_add(c0, c1, v.z & 7);
    packed_add(c0, c1, v.w & 7);
  }
#pragma unroll
  for (int m = 1; m < 64; m <<= 1) {
    c0 += __shfl_xor(c0, m);
    c1 += __shfl_xor(c1, m);
  }
  if (lane == 0) { w0s[wid] = c0; w1s[wid] = c1; }
  __syncthreads();

  // ---- serial stable rank of this block's 16 entries --------------------
  if (tid == 0) {
    u64 p0 = w0s[0] + w0s[1] + w0s[2] + w0s[3];
    u64 p1 = w1s[0] + w1s[1] + w1s[2] + w1s[3];
    const float4* __restrict__ ew4 = reinterpret_cast<const float4*>(ew);
#pragma unroll
    for (int q = 0; q < 4; ++q) {
      const int4 v = te4[(E0 >> 2) + q];
      const float4 w = ew4[(E0 >> 2) + q];
      const int ee[4] = {v.x & 7, v.y & 7, v.z & 7, v.w & 7};
      const float wv[4] = {w.x, w.y, w.z, w.w};
      float s01 = 0.f, s23 = 0.f;
#pragma unroll
      for (int k = 0; k < 4; ++k) {
        const int e = ee[k];
        const int r = packed_get(p0, p1, e);
        packed_add(p0, p1, e);
        if (r < C) {
          if (k < 2) s01 += wv[k]; else s23 += wv[k];
        }
      }
      scale_s[q * 2 + 0] = s01;
      scale_s[q * 2 + 1] = s23;
    }
  }
  __syncthreads();

  // ---- stream: out = x * scale + bias -----------------------------------
  float4* __restrict__ o4 =
      reinterpret_cast<float4*>(out) + b * (ROWS_PB * 256);
  {
    float s;
    float4 ov;
#define EMIT(K, XV)                                         \
    s = scale_s[K];                                         \
    ov.x = XV.x * s + bv.x; ov.y = XV.y * s + bv.y;         \
    ov.z = XV.z * s + bv.z; ov.w = XV.w * s + bv.w;         \
    o4[K * 256 + tid] = ov;
    EMIT(0, xv0) EMIT(1, xv1) EMIT(2, xv2) EMIT(3, xv3)
    EMIT(4, xv4) EMIT(5, xv5) EMIT(6, xv6) EMIT(7, xv7)
#undef EMIT
  }
}

extern "C" void kernel_launch(void* const* d_in, const int* in_sizes, int n_in,
                              void* d_out, int out_size, void* d_ws,
                              size_t ws_size, hipStream_t stream) {
  // setup_inputs order: x, cond, mask, scores, expert_weights, top_experts, bias
  const float* x    = (const float*)d_in[0];
  const float* ew   = (const float*)d_in[4];
  const int*   te   = (const int*)d_in[5];
  const float* bias = (const float*)d_in[6];
  float* out = (float*)d_out;
  int* hist = (int*)d_ws;  // 256 ints

  const int T = in_sizes[5];       // 32768 flat assignments
  const int C = T / N_EXPERTS;     // 4096 expert capacity
  const int nblocks = (in_sizes[0] / 1024) / ROWS_PB;  // 2048

  hist_kernel<<<32, 256, 0, stream>>>(te, hist);
  fused_kernel<<<nblocks, 256, 0, stream>>>(x, te, ew, hist, bias, out, C);
}